// Round 1
// baseline (929.292 us; speedup 1.0000x reference)
//
#include <hip/hip_runtime.h>

typedef __attribute__((ext_vector_type(8))) short bf16x8;
typedef __attribute__((ext_vector_type(8))) unsigned short ushort8;
typedef __attribute__((ext_vector_type(4))) float f32x4;

__device__ __forceinline__ unsigned short f32_to_bf16(float f) {
    union { float f; unsigned int u; } v;
    v.f = f;
    unsigned int r = v.u + (0x7fffu + ((v.u >> 16) & 1u));  // RNE
    return (unsigned short)(r >> 16);
}

__device__ __forceinline__ void gload_lds16(const void* g, void* l) {
    __builtin_amdgcn_global_load_lds(
        (const __attribute__((address_space(1))) unsigned int*)g,
        (__attribute__((address_space(3))) unsigned int*)l, 16, 0, 0);
}

// ---------------- conversion kernels ----------------
__global__ void convert_x_kernel(const float* __restrict__ x,
                                 unsigned short* __restrict__ xb, long n8) {
    long i = (long)blockIdx.x * blockDim.x + threadIdx.x;
    const long stride = (long)gridDim.x * blockDim.x;
    for (; i < n8; i += stride) {
        const float4* p = (const float4*)(x + i * 8);
        float4 a = p[0], b = p[1];
        ushort8 v;
        v[0] = f32_to_bf16(a.x); v[1] = f32_to_bf16(a.y);
        v[2] = f32_to_bf16(a.z); v[3] = f32_to_bf16(a.w);
        v[4] = f32_to_bf16(b.x); v[5] = f32_to_bf16(b.y);
        v[6] = f32_to_bf16(b.z); v[7] = f32_to_bf16(b.w);
        *(ushort8*)(xb + i * 8) = v;
    }
}

__global__ void convert_q_kernel(const int* __restrict__ q,
                                 unsigned short* __restrict__ qb, long n8) {
    long i = (long)blockIdx.x * blockDim.x + threadIdx.x;
    const long stride = (long)gridDim.x * blockDim.x;
    for (; i < n8; i += stride) {
        const int4* p = (const int4*)(q + i * 8);
        int4 a = p[0], b = p[1];
        ushort8 v;
        v[0] = f32_to_bf16((float)a.x); v[1] = f32_to_bf16((float)a.y);
        v[2] = f32_to_bf16((float)a.z); v[3] = f32_to_bf16((float)a.w);
        v[4] = f32_to_bf16((float)b.x); v[5] = f32_to_bf16((float)b.y);
        v[6] = f32_to_bf16((float)b.z); v[7] = f32_to_bf16((float)b.w);
        *(ushort8*)(qb + i * 8) = v;
    }
}

// ---------------- GEMM: C[m,n] = sum_k A[m,k]*B[n,k], out = C*scale[n]+bias[n] ----
// 128x128 tile, BK=64, 4 waves (2x2), each wave 64x64 via 4x4 frags of 16x16x32 bf16.
template <bool PRECONV>
__global__ __launch_bounds__(256) void qgemm_kernel(
    const void* __restrict__ Ain, const void* __restrict__ Bin,
    const float* __restrict__ scale, const float* __restrict__ bias,
    float* __restrict__ C, int M, int N, int K) {
    constexpr int BM = 128, BN = 128, BK = 64;
    __shared__ unsigned short lA[BM * BK];
    __shared__ unsigned short lB[BN * BK];

    const int t    = threadIdx.x;
    const int lane = t & 63;
    const int w    = t >> 6;
    const int wr   = w >> 1;
    const int wc   = w & 1;
    const int m0   = blockIdx.y * BM;
    const int n0   = blockIdx.x * BN;
    const int l15  = lane & 15;
    const int l4   = lane >> 4;

    f32x4 acc[4][4];
#pragma unroll
    for (int m = 0; m < 4; ++m)
#pragma unroll
        for (int n = 0; n < 4; ++n)
            acc[m][n] = (f32x4){0.f, 0.f, 0.f, 0.f};

    for (int k0 = 0; k0 < K; k0 += BK) {
        __syncthreads();  // previous tile's compute done before overwrite
        if constexpr (PRECONV) {
            const unsigned short* A = (const unsigned short*)Ain;
            const unsigned short* B = (const unsigned short*)Bin;
#pragma unroll
            for (int i = 0; i < 4; ++i) {
                const int base = i * 4096 + w * 1024;   // wave-uniform LDS byte base
                const int off  = base + lane * 16;      // per-lane tile byte offset
                const int row  = off >> 7;              // 128 B per row (BK*2)
                const int col  = (off & 127) >> 1;      // bf16 element col
                gload_lds16(A + (size_t)(m0 + row) * K + k0 + col, (char*)lA + base);
                gload_lds16(B + (size_t)(n0 + row) * K + k0 + col, (char*)lB + base);
            }
            asm volatile("s_waitcnt vmcnt(0)" ::: "memory");
        } else {
            // fallback: reg-stage + on-the-fly convert (no workspace needed)
            const float* Af = (const float*)Ain;
            const int*   Bi = (const int*)Bin;
#pragma unroll
            for (int i = 0; i < 4; ++i) {
                const int off = i * 4096 + w * 1024 + lane * 16;
                const int row = off >> 7;
                const int col = (off & 127) >> 1;
                const float* pa = Af + (size_t)(m0 + row) * K + k0 + col;
                float4 a0 = *(const float4*)pa;
                float4 a1 = *(const float4*)(pa + 4);
                ushort8 va;
                va[0] = f32_to_bf16(a0.x); va[1] = f32_to_bf16(a0.y);
                va[2] = f32_to_bf16(a0.z); va[3] = f32_to_bf16(a0.w);
                va[4] = f32_to_bf16(a1.x); va[5] = f32_to_bf16(a1.y);
                va[6] = f32_to_bf16(a1.z); va[7] = f32_to_bf16(a1.w);
                *(ushort8*)((char*)lA + off) = va;
                const int* pb = Bi + (size_t)(n0 + row) * K + k0 + col;
                int4 b0 = *(const int4*)pb;
                int4 b1 = *(const int4*)(pb + 4);
                ushort8 vb;
                vb[0] = f32_to_bf16((float)b0.x); vb[1] = f32_to_bf16((float)b0.y);
                vb[2] = f32_to_bf16((float)b0.z); vb[3] = f32_to_bf16((float)b0.w);
                vb[4] = f32_to_bf16((float)b1.x); vb[5] = f32_to_bf16((float)b1.y);
                vb[6] = f32_to_bf16((float)b1.z); vb[7] = f32_to_bf16((float)b1.w);
                *(ushort8*)((char*)lB + off) = vb;
            }
        }
        __syncthreads();

#pragma unroll
        for (int kk = 0; kk < BK; kk += 32) {
            bf16x8 af[4], bfr[4];
#pragma unroll
            for (int m = 0; m < 4; ++m)
                af[m] = *(const bf16x8*)&lA[(wr * 64 + m * 16 + l15) * BK + kk + l4 * 8];
#pragma unroll
            for (int n = 0; n < 4; ++n)
                bfr[n] = *(const bf16x8*)&lB[(wc * 64 + n * 16 + l15) * BK + kk + l4 * 8];
#pragma unroll
            for (int m = 0; m < 4; ++m)
#pragma unroll
                for (int n = 0; n < 4; ++n)
                    acc[m][n] = __builtin_amdgcn_mfma_f32_16x16x32_bf16(
                        af[m], bfr[n], acc[m][n], 0, 0, 0);
        }
    }

    // epilogue: out = acc * scale[col] + bias[col]
    // C/D layout (m89-verified): col = lane&15, row = (lane>>4)*4 + j
#pragma unroll
    for (int n = 0; n < 4; ++n) {
        const int col = n0 + wc * 64 + n * 16 + l15;
        const float sc = scale[col];
        const float bs = bias[col];
#pragma unroll
        for (int m = 0; m < 4; ++m) {
            const int row0 = m0 + wr * 64 + m * 16 + l4 * 4;
#pragma unroll
            for (int j = 0; j < 4; ++j) {
                C[(size_t)(row0 + j) * N + col] = fmaf(acc[m][n][j], sc, bs);
            }
        }
    }
}

extern "C" void kernel_launch(void* const* d_in, const int* in_sizes, int n_in,
                              void* d_out, int out_size, void* d_ws, size_t ws_size,
                              hipStream_t stream) {
    const float* x     = (const float*)d_in[0];
    const int*   q     = (const int*)d_in[1];
    const float* scale = (const float*)d_in[2];
    const float* bias  = (const float*)d_in[3];
    float*       out   = (float*)d_out;

    const int K = in_sizes[2];            // 4096 (scale length == in_features)
    const int N = in_sizes[1] / K;        // 4096
    const int M = in_sizes[0] / K;        // 16384

    const size_t xb_elems = (size_t)M * K;
    const size_t qb_elems = (size_t)N * K;
    const size_t need     = (xb_elems + qb_elems) * sizeof(unsigned short);

    dim3 grid(N / 128, M / 128);
    if (ws_size >= need) {
        unsigned short* xb = (unsigned short*)d_ws;
        unsigned short* qb = xb + xb_elems;
        convert_x_kernel<<<2048, 256, 0, stream>>>(x, xb, (long)(xb_elems / 8));
        convert_q_kernel<<<2048, 256, 0, stream>>>(q, qb, (long)(qb_elems / 8));
        qgemm_kernel<true><<<grid, 256, 0, stream>>>(xb, qb, scale, bias, out, M, N, K);
    } else {
        qgemm_kernel<false><<<grid, 256, 0, stream>>>(x, q, scale, bias, out, M, N, K);
    }
}

// Round 2
// 571.232 us; speedup vs baseline: 1.6268x; 1.6268x over previous
//
#include <hip/hip_runtime.h>

typedef __attribute__((ext_vector_type(8))) short bf16x8;
typedef __attribute__((ext_vector_type(8))) unsigned short ushort8;
typedef __attribute__((ext_vector_type(4))) float f32x4;

__device__ __forceinline__ unsigned short f32_to_bf16(float f) {
    union { float f; unsigned int u; } v;
    v.f = f;
    unsigned int r = v.u + (0x7fffu + ((v.u >> 16) & 1u));  // RNE
    return (unsigned short)(r >> 16);
}

__device__ __forceinline__ void gload_lds16(const void* g, void* l) {
    __builtin_amdgcn_global_load_lds(
        (const __attribute__((address_space(1))) unsigned int*)g,
        (__attribute__((address_space(3))) unsigned int*)l, 16, 0, 0);
}

// ---------------- conversion kernels ----------------
__global__ void convert_x_kernel(const float* __restrict__ x,
                                 unsigned short* __restrict__ xb, long n8) {
    long i = (long)blockIdx.x * blockDim.x + threadIdx.x;
    const long stride = (long)gridDim.x * blockDim.x;
    for (; i < n8; i += stride) {
        const float4* p = (const float4*)(x + i * 8);
        float4 a = p[0], b = p[1];
        ushort8 v;
        v[0] = f32_to_bf16(a.x); v[1] = f32_to_bf16(a.y);
        v[2] = f32_to_bf16(a.z); v[3] = f32_to_bf16(a.w);
        v[4] = f32_to_bf16(b.x); v[5] = f32_to_bf16(b.y);
        v[6] = f32_to_bf16(b.z); v[7] = f32_to_bf16(b.w);
        *(ushort8*)(xb + i * 8) = v;
    }
}

__global__ void convert_q_kernel(const int* __restrict__ q,
                                 unsigned short* __restrict__ qb, long n8) {
    long i = (long)blockIdx.x * blockDim.x + threadIdx.x;
    const long stride = (long)gridDim.x * blockDim.x;
    for (; i < n8; i += stride) {
        const int4* p = (const int4*)(q + i * 8);
        int4 a = p[0], b = p[1];
        ushort8 v;
        v[0] = f32_to_bf16((float)a.x); v[1] = f32_to_bf16((float)a.y);
        v[2] = f32_to_bf16((float)a.z); v[3] = f32_to_bf16((float)a.w);
        v[4] = f32_to_bf16((float)b.x); v[5] = f32_to_bf16((float)b.y);
        v[6] = f32_to_bf16((float)b.z); v[7] = f32_to_bf16((float)b.w);
        *(ushort8*)(qb + i * 8) = v;
    }
}

// ---------------- 256x256 8-phase GEMM (T1+T2+T3+T4+T5) ----------------
// C[m,n] = sum_k A[m,k]*B[n,k]; out = C*scale[n] + bias[n]
// A = xb [M][K] bf16, B = qb [N][K] bf16. BM=BN=256, BK=64, 512 thr (8 waves 2x4).
// LDS: A bufs 2x32KB @0, B bufs 2x32KB @65536. Half-tile = 128 rows x 64 bf16 = 16KB.
// Swizzle: logical 16B chunk (r, s) stored at physical slot s^(r&7) within row r.
__global__ __launch_bounds__(512, 2) void qgemm8_kernel(
    const unsigned short* __restrict__ A, const unsigned short* __restrict__ B,
    const float* __restrict__ scale, const float* __restrict__ bias,
    float* __restrict__ C, int M, int N, int K) {
    extern __shared__ char sm[];

    const int tid  = threadIdx.x;
    const int lane = tid & 63;
    const int w    = tid >> 6;
    const int wr   = w >> 2;                  // 0..1
    const int wc   = w & 3;                   // 0..3
    const int l15  = lane & 15;
    const int l4   = lane >> 4;
    const int r7   = l15 & 7;

    // T1: bijective XCD swizzle (gridDim.x % 8 == 0 by construction)
    const int nwg = gridDim.x;
    const int bid = blockIdx.x;
    const int swz = (bid & 7) * (nwg >> 3) + (bid >> 3);
    const int nbx = N >> 8;
    const int m0  = (swz / nbx) << 8;
    const int n0  = (swz % nbx) << 8;

    // per-thread staging constants: chunk c -> r=c>>3, s=(c&7)^(r&7); src elem = r*K + s*8
    const int c0 = tid, c1 = tid + 512;
    const size_t inv0 = (size_t)(c0 >> 3) * K + (size_t)((((c0 & 7) ^ ((c0 >> 3) & 7))) << 3);
    const size_t inv1 = (size_t)(c1 >> 3) * K + (size_t)((((c1 & 7) ^ ((c1 >> 3) & 7))) << 3);
    const int ldst0 = w << 10;                // wave-uniform LDS byte offset, round 0
    const int ldst1 = (w << 10) + 8192;       // round 1

#define STAGE(ldsHalf, gsrc) do {                         \
        gload_lds16((gsrc) + inv0, (ldsHalf) + ldst0);    \
        gload_lds16((gsrc) + inv1, (ldsHalf) + ldst1); } while (0)

    // fragment read offsets (bytes)
    const int aRow0 = (wr * 128 + l15) * 128;  // + m*2048
    const int bRow0 = (wc * 64 + l15) * 128;   // + n*2048
    const int sl0   = ((0 + l4) ^ r7) << 4;    // kk=0 slot
    const int sl1   = ((4 + l4) ^ r7) << 4;    // kk=1 slot

    const unsigned short* pA = A + (size_t)m0 * K;
    const unsigned short* pB = B + (size_t)n0 * K;
    const size_t hK = (size_t)128 * K;
    const int NT = K >> 6;

    f32x4 acc[8][4];
#pragma unroll
    for (int m = 0; m < 8; ++m)
#pragma unroll
        for (int n = 0; n < 4; ++n) acc[m][n] = (f32x4){0.f, 0.f, 0.f, 0.f};

    // ---- prologue: tile0 (4 halves) + A0(tile1); leave A0(1) in flight ----
    STAGE(sm + 0,     pA);            // A0(0)
    STAGE(sm + 16384, pA + hK);       // A1(0)
    STAGE(sm + 65536, pB);            // B0(0)
    STAGE(sm + 81920, pB + hK);       // B1(0)
    if (NT > 1) STAGE(sm + 32768, pA + 64);   // A0(1)
    asm volatile("s_waitcnt vmcnt(2)" ::: "memory");
    __builtin_amdgcn_s_barrier();

#define LGKM0() do { asm volatile("s_waitcnt lgkmcnt(0)" ::: "memory"); \
                     __builtin_amdgcn_sched_barrier(0); } while (0)
#define MFMA_QUAD(MB, NB)                                                      \
    _Pragma("unroll") for (int kk = 0; kk < 2; ++kk)                           \
    _Pragma("unroll") for (int m = 0; m < 4; ++m)                              \
    _Pragma("unroll") for (int n = 0; n < 2; ++n)                              \
        acc[(MB) + m][(NB) + n] = __builtin_amdgcn_mfma_f32_16x16x32_bf16(     \
            aF[m][kk], bF[(NB) + n][kk], acc[(MB) + m][(NB) + n], 0, 0, 0);

    for (int t = 0; t < NT; ++t) {
        char* Ab = sm + (t & 1) * 32768;
        char* Bb = sm + 65536 + (t & 1) * 32768;
        char* An = sm + ((t & 1) ^ 1) * 32768;
        char* Bn = sm + 65536 + ((t & 1) ^ 1) * 32768;
        const int k1 = (t + 1) << 6;
        const int k2 = (t + 2) << 6;
        bf16x8 aF[4][2], bF[4][2];

        // ---- P0: read A(mh0) + B(n0,n1); stage A1(t+1); MFMA q(0,0) ----
#pragma unroll
        for (int m = 0; m < 4; ++m) {
            aF[m][0] = *(const bf16x8*)(Ab + aRow0 + m * 2048 + sl0);
            aF[m][1] = *(const bf16x8*)(Ab + aRow0 + m * 2048 + sl1);
        }
#pragma unroll
        for (int n = 0; n < 2; ++n) {
            bF[n][0] = *(const bf16x8*)(Bb + bRow0 + n * 2048 + sl0);
            bF[n][1] = *(const bf16x8*)(Bb + bRow0 + n * 2048 + sl1);
        }
        if (t + 1 < NT) STAGE(An + 16384, pA + hK + k1);
        __builtin_amdgcn_s_barrier();
        LGKM0();
        __builtin_amdgcn_s_setprio(1);
        MFMA_QUAD(0, 0);
        __builtin_amdgcn_s_setprio(0);
        __builtin_amdgcn_s_barrier();

        // ---- P1: read B(n2,n3); stage B0(t+1); MFMA q(0,1) ----
#pragma unroll
        for (int n = 2; n < 4; ++n) {
            bF[n][0] = *(const bf16x8*)(Bb + bRow0 + n * 2048 + sl0);
            bF[n][1] = *(const bf16x8*)(Bb + bRow0 + n * 2048 + sl1);
        }
        if (t + 1 < NT) STAGE(Bn, pB + k1);
        __builtin_amdgcn_s_barrier();
        LGKM0();
        __builtin_amdgcn_s_setprio(1);
        MFMA_QUAD(0, 2);
        __builtin_amdgcn_s_setprio(0);
        __builtin_amdgcn_s_barrier();

        // ---- P2: read A(mh1); stage B1(t+1); MFMA q(1,0) ----
#pragma unroll
        for (int m = 0; m < 4; ++m) {
            aF[m][0] = *(const bf16x8*)(Ab + aRow0 + (m + 4) * 2048 + sl0);
            aF[m][1] = *(const bf16x8*)(Ab + aRow0 + (m + 4) * 2048 + sl1);
        }
        if (t + 1 < NT) STAGE(Bn + 16384, pB + hK + k1);
        __builtin_amdgcn_s_barrier();
        LGKM0();
        __builtin_amdgcn_s_setprio(1);
        MFMA_QUAD(4, 0);
        __builtin_amdgcn_s_setprio(0);
        __builtin_amdgcn_s_barrier();

        // ---- P3: stage A0(t+2) into current A buf; MFMA q(1,1); counted vmcnt ----
        if (t + 2 < NT) STAGE(Ab, pA + k2);
        __builtin_amdgcn_s_setprio(1);
        MFMA_QUAD(4, 2);
        __builtin_amdgcn_s_setprio(0);
        if (t + 2 < NT) asm volatile("s_waitcnt vmcnt(2)" ::: "memory");
        else            asm volatile("s_waitcnt vmcnt(0)" ::: "memory");
        __builtin_amdgcn_s_barrier();
    }

    // ---- epilogue: out = acc*scale[col] + bias[col] ----
#pragma unroll
    for (int n = 0; n < 4; ++n) {
        const int col = n0 + wc * 64 + n * 16 + l15;
        const float sc = scale[col];
        const float bs = bias[col];
#pragma unroll
        for (int m = 0; m < 8; ++m) {
            const int row0 = m0 + wr * 128 + m * 16 + l4 * 4;
#pragma unroll
            for (int j = 0; j < 4; ++j)
                C[(size_t)(row0 + j) * N + col] = fmaf(acc[m][n][j], sc, bs);
        }
    }
#undef STAGE
#undef LGKM0
#undef MFMA_QUAD
}

// ---------------- fallback (no workspace): round-1 2-phase, on-the-fly convert ----
__global__ __launch_bounds__(256) void qgemm_fb_kernel(
    const float* __restrict__ Af, const int* __restrict__ Bi,
    const float* __restrict__ scale, const float* __restrict__ bias,
    float* __restrict__ C, int M, int N, int K) {
    constexpr int BK = 64;
    __shared__ unsigned short lA[128 * BK];
    __shared__ unsigned short lB[128 * BK];
    const int t = threadIdx.x, lane = t & 63, w = t >> 6;
    const int wr = w >> 1, wc = w & 1;
    const int m0 = blockIdx.y * 128, n0 = blockIdx.x * 128;
    const int l15 = lane & 15, l4 = lane >> 4;
    f32x4 acc[4][4];
#pragma unroll
    for (int m = 0; m < 4; ++m)
#pragma unroll
        for (int n = 0; n < 4; ++n) acc[m][n] = (f32x4){0.f, 0.f, 0.f, 0.f};
    for (int k0 = 0; k0 < K; k0 += BK) {
        __syncthreads();
#pragma unroll
        for (int i = 0; i < 4; ++i) {
            const int off = i * 4096 + w * 1024 + lane * 16;
            const int row = off >> 7;
            const int col = (off & 127) >> 1;
            const float* pa = Af + (size_t)(m0 + row) * K + k0 + col;
            float4 a0 = *(const float4*)pa;
            float4 a1 = *(const float4*)(pa + 4);
            ushort8 va;
            va[0] = f32_to_bf16(a0.x); va[1] = f32_to_bf16(a0.y);
            va[2] = f32_to_bf16(a0.z); va[3] = f32_to_bf16(a0.w);
            va[4] = f32_to_bf16(a1.x); va[5] = f32_to_bf16(a1.y);
            va[6] = f32_to_bf16(a1.z); va[7] = f32_to_bf16(a1.w);
            *(ushort8*)((char*)lA + off) = va;
            const int* pb = Bi + (size_t)(n0 + row) * K + k0 + col;
            int4 b0 = *(const int4*)pb;
            int4 b1 = *(const int4*)(pb + 4);
            ushort8 vb;
            vb[0] = f32_to_bf16((float)b0.x); vb[1] = f32_to_bf16((float)b0.y);
            vb[2] = f32_to_bf16((float)b0.z); vb[3] = f32_to_bf16((float)b0.w);
            vb[4] = f32_to_bf16((float)b1.x); vb[5] = f32_to_bf16((float)b1.y);
            vb[6] = f32_to_bf16((float)b1.z); vb[7] = f32_to_bf16((float)b1.w);
            *(ushort8*)((char*)lB + off) = vb;
        }
        __syncthreads();
#pragma unroll
        for (int kk = 0; kk < BK; kk += 32) {
            bf16x8 af[4], bfr[4];
#pragma unroll
            for (int m = 0; m < 4; ++m)
                af[m] = *(const bf16x8*)&lA[(wr * 64 + m * 16 + l15) * BK + kk + l4 * 8];
#pragma unroll
            for (int n = 0; n < 4; ++n)
                bfr[n] = *(const bf16x8*)&lB[(wc * 64 + n * 16 + l15) * BK + kk + l4 * 8];
#pragma unroll
            for (int m = 0; m < 4; ++m)
#pragma unroll
                for (int n = 0; n < 4; ++n)
                    acc[m][n] = __builtin_amdgcn_mfma_f32_16x16x32_bf16(
                        af[m], bfr[n], acc[m][n], 0, 0, 0);
        }
    }
#pragma unroll
    for (int n = 0; n < 4; ++n) {
        const int col = n0 + wc * 64 + n * 16 + l15;
        const float sc = scale[col], bs = bias[col];
#pragma unroll
        for (int m = 0; m < 4; ++m) {
            const int row0 = m0 + wr * 64 + m * 16 + l4 * 4;
#pragma unroll
            for (int j = 0; j < 4; ++j)
                C[(size_t)(row0 + j) * N + col] = fmaf(acc[m][n][j], sc, bs);
        }
    }
}

extern "C" void kernel_launch(void* const* d_in, const int* in_sizes, int n_in,
                              void* d_out, int out_size, void* d_ws, size_t ws_size,
                              hipStream_t stream) {
    const float* x     = (const float*)d_in[0];
    const int*   q     = (const int*)d_in[1];
    const float* scale = (const float*)d_in[2];
    const float* bias  = (const float*)d_in[3];
    float*       out   = (float*)d_out;

    const int K = in_sizes[2];
    const int N = in_sizes[1] / K;
    const int M = in_sizes[0] / K;

    const size_t xb_elems = (size_t)M * K;
    const size_t qb_elems = (size_t)N * K;
    const size_t need     = (xb_elems + qb_elems) * sizeof(unsigned short);

    if (ws_size >= need && (M % 256) == 0 && (N % 256) == 0 && (K % 64) == 0) {
        unsigned short* xb = (unsigned short*)d_ws;
        unsigned short* qb = xb + xb_elems;
        convert_x_kernel<<<2048, 256, 0, stream>>>(x, xb, (long)(xb_elems / 8));
        convert_q_kernel<<<2048, 256, 0, stream>>>(q, qb, (long)(qb_elems / 8));
        dim3 grid((M / 256) * (N / 256));
        qgemm8_kernel<<<grid, 512, 131072, stream>>>(xb, qb, scale, bias, out, M, N, K);
    } else {
        dim3 grid(N / 128, M / 128);
        qgemm_fb_kernel<<<grid, 256, 0, stream>>>(x, q, scale, bias, out, M, N, K);
    }
}